// Round 11
// baseline (92.180 us; speedup 1.0000x reference)
//
#include <hip/hip_runtime.h>
#include <hip/hip_bf16.h>

#define ALPHA_ (-30.0f)
#define EPS_ (1e-4f)
#define LOG2E_ (1.4426950408889634f)

typedef short bf16x8 __attribute__((ext_vector_type(8)));
typedef float f32x4 __attribute__((ext_vector_type(4)));

__device__ __forceinline__ short f2bf(float f) {
  __hip_bfloat16 h = __float2bfloat16(f);
  return __builtin_bit_cast(short, h);
}

__device__ __forceinline__ bf16x8 ld_a(const short* p) {
  int2 lo = *reinterpret_cast<const int2*>(p);      // 8B aligned
  int2 hi = *reinterpret_cast<const int2*>(p + 4);
  union { int i[4]; bf16x8 v; } u;
  u.i[0] = lo.x; u.i[1] = lo.y; u.i[2] = hi.x; u.i[3] = hi.y;
  return u.v;
}

__device__ __forceinline__ bf16x8 ld_b(const short* p) {
  union { int4 i; bf16x8 v; } u;
  u.i = *reinterpret_cast<const int4*>(p);          // 16B aligned
  return u.v;
}

// Proven-best configuration (bench: dur_us 53.57, R3): block = (row, scale),
// 4 waves, 64 shapelets/block, CL=2192 (32B copy stagger -> 2-way LDS
// aliasing = free), launch_bounds(256,2) -> VGPR 84, zero spill.
// LDS layout (bytes):
//   XC  @ 0     : 4 copies x 2192 bf16 (copy c: Cc[j] = bf16(x[j+c]))  = 17536
//   PS  @ 17536 : prefix sums of x^2, f32[2049] (+pad)                 =  8208
//   SH  @ 25744 : shapelets bf16 [64][L]   (phase A)                   <= 12288
//   SX  @ 25744 : sumx2 f32[2048]          (phase B, overlays SH)
//   S2  @ 38032 : f32[64]
//   RED @ 38288 : f32[512]
#define XC_OFF 0
#define PS_OFF 17536
#define R2_OFF 25744
#define S2_OFF 38032
#define RED_OFF 38288
#define SMEM_BYTES 40352
#define CL 2192

template <int L, int SCALE>
__device__ __forceinline__ void feat_impl(const float* __restrict__ series,
                                          const float* __restrict__ shp,
                                          float* __restrict__ F,
                                          char* smem) {
  constexpr int T = 2048;
  constexpr int W = T - L + 1;
  constexpr int KT = L / 32;
  constexpr int NIT = (W + 63) / 64;

  short* xc = (short*)(smem + XC_OFF);
  float* ps = (float*)(smem + PS_OFF);
  short* sh = (short*)(smem + R2_OFF);
  float* sx = (float*)(smem + R2_OFF);
  float* s2 = (float*)(smem + S2_OFF);
  float* red = (float*)(smem + RED_OFF);

  const int n = blockIdx.x;
  const int tid = threadIdx.x;
  const int lane = tid & 63;
  const int wv = tid >> 6;
  const int col = lane & 15;
  const int kg = lane >> 4;

  // ---------------- phase 1: stage x (f32 scan + 4 shifted bf16 copies),
  // shapelets (bf16), s2 ----------------
  const float* srow = series + (size_t)n * T;
  float xv[8];
  short bv[8];
  {
    float4 v0 = *reinterpret_cast<const float4*>(srow + tid * 8);
    float4 v1 = *reinterpret_cast<const float4*>(srow + tid * 8 + 4);
    xv[0] = v0.x; xv[1] = v0.y; xv[2] = v0.z; xv[3] = v0.w;
    xv[4] = v1.x; xv[5] = v1.y; xv[6] = v1.z; xv[7] = v1.w;
#pragma unroll
    for (int i = 0; i < 8; ++i) bv[i] = f2bf(xv[i]);
  }
  float loc[8];
  float run = 0.f;
#pragma unroll
  for (int i = 0; i < 8; ++i) { run += xv[i] * xv[i]; loc[i] = run; }
  red[tid] = run;
  __syncthreads();
  for (int off = 1; off < 256; off <<= 1) {
    float add = (tid >= off) ? red[tid - off] : 0.f;
    __syncthreads();
    red[tid] += add;
    __syncthreads();
  }
  float excl = red[tid] - run;
#pragma unroll
  for (int i = 0; i < 8; ++i) ps[tid * 8 + 1 + i] = excl + loc[i];
  if (tid == 0) ps[0] = 0.f;

#pragma unroll
  for (int c = 0; c < 4; ++c) {
    int j0 = tid * 8 - c;
#pragma unroll
    for (int i = 0; i < 8; ++i) {
      int j = j0 + i;
      if (j >= 0) xc[c * CL + j] = bv[i];
    }
  }
#pragma unroll
  for (int c = 0; c < 4; ++c)
    for (int j = 2048 - c + tid; j < CL; j += 256) xc[c * CL + j] = 0;

  for (int i = tid; i < 64 * L; i += 256) sh[i] = f2bf(shp[i]);
  if (tid < 64) {
    float s = 0.f;
    for (int l = 0; l < L; ++l) { float v = shp[tid * L + l]; s += v * v; }
    s2[tid] = s;
  }
  __syncthreads();

  // ---------------- phase 2: B fragments + s2 to registers ----------------
  bf16x8 bfr[KT][4];
#pragma unroll
  for (int kt = 0; kt < KT; ++kt)
#pragma unroll
    for (int nt = 0; nt < 4; ++nt)
      bfr[kt][nt] = ld_b(sh + (nt * 16 + col) * L + kt * 32 + kg * 8);
  float s2c[4];
#pragma unroll
  for (int nt = 0; nt < 4; ++nt) s2c[nt] = s2[nt * 16 + col];
  __syncthreads();

  // ---------------- phase 3: sumx2 (overlays SH) ----------------
  for (int w = tid; w < 2048; w += 256)
    sx[w] = (w < W) ? (ps[w + L] - ps[w]) : 0.f;
  __syncthreads();

  // ---------------- phase 4: main loop (barrier-free) ----------------
  constexpr float CE = ALPHA_ * LOG2E_ / (float)L;
  constexpr float INVL = 1.0f / (float)L;
  const int cc = lane & 3;
  const short* abase = xc + cc * CL + ((lane & 15) - cc + 8 * kg);

  float esum[4] = {0.f, 0.f, 0.f, 0.f};
  float dsum[4] = {0.f, 0.f, 0.f, 0.f};

  for (int it = 0; it < NIT; ++it) {
    const int w0 = it * 64 + wv * 16;
    const short* ap = abase + w0;
    f32x4 acc[4];
#pragma unroll
    for (int nt = 0; nt < 4; ++nt) acc[nt] = (f32x4){0.f, 0.f, 0.f, 0.f};
#pragma unroll
    for (int kt = 0; kt < KT; ++kt) {
      bf16x8 a = ld_a(ap + kt * 32);
#pragma unroll
      for (int nt = 0; nt < 4; ++nt)
        acc[nt] = __builtin_amdgcn_mfma_f32_16x16x32_bf16(a, bfr[kt][nt],
                                                          acc[nt], 0, 0, 0);
    }
    const int wbase = w0 + kg * 4;
    float sxa[4];
    {
      float4 v = *reinterpret_cast<const float4*>(sx + wbase);
      sxa[0] = v.x; sxa[1] = v.y; sxa[2] = v.z; sxa[3] = v.w;
    }
#pragma unroll
    for (int nt = 0; nt < 4; ++nt) {
#pragma unroll
      for (int r = 0; r < 4; ++r) {
        float t = fmaf(-2.f, acc[nt][r], sxa[r] + s2c[nt]);  // L * d
        float e = exp2f(t * CE) + EPS_;
        float em = (wbase + r < W) ? e : 0.f;
        esum[nt] += em;
        dsum[nt] = fmaf(t, em, dsum[nt]);
      }
    }
  }

  // ---------------- phase 5: reduce ----------------
  float fe[4], fd[4];
#pragma unroll
  for (int nt = 0; nt < 4; ++nt) {
    float es = esum[nt], ds = dsum[nt];
    es += __shfl_xor(es, 16, 64);
    es += __shfl_xor(es, 32, 64);
    ds += __shfl_xor(ds, 16, 64);
    ds += __shfl_xor(ds, 32, 64);
    fe[nt] = es; fd[nt] = ds;
  }
  __syncthreads();
  if (lane < 16) {
#pragma unroll
    for (int nt = 0; nt < 4; ++nt) {
      red[wv * 64 + nt * 16 + lane] = fe[nt];
      red[256 + wv * 64 + nt * 16 + lane] = fd[nt];
    }
  }
  __syncthreads();
  if (tid < 64) {
    float es = red[tid] + red[64 + tid] + red[128 + tid] + red[192 + tid];
    float ds = red[256 + tid] + red[320 + tid] + red[384 + tid] + red[448 + tid];
    F[n * 192 + SCALE * 64 + tid] = (ds / es) * INVL;
  }
}

__global__ void __launch_bounds__(256, 2)
feat_kernel(const float* __restrict__ series, const float* __restrict__ shp1,
            const float* __restrict__ shp2, const float* __restrict__ shp3,
            float* __restrict__ F) {
  __shared__ __align__(16) char smem[SMEM_BYTES];
  if (blockIdx.y == 0)
    feat_impl<32, 0>(series, shp1, F, smem);
  else if (blockIdx.y == 1)
    feat_impl<64, 1>(series, shp2, F, smem);
  else
    feat_impl<96, 2>(series, shp3, F, smem);
}

// ---------------------------------------------------------------------------
// Logits + softmax: out[n, :] = softmax(F[n, :] @ W + b)
// ---------------------------------------------------------------------------
__global__ void __launch_bounds__(256) logits_kernel(const float* __restrict__ F,
                                                     const float* __restrict__ Wm,
                                                     const float* __restrict__ bv,
                                                     float* __restrict__ out) {
  __shared__ float Ws[1920];
  __shared__ float bs[16];
  const int tid = threadIdx.x;
  for (int i = tid; i < 1920; i += 256) Ws[i] = Wm[i];
  if (tid < 10) bs[tid] = bv[tid];
  __syncthreads();

  const int n = blockIdx.x * 256 + tid;
  float acc[10];
#pragma unroll
  for (int c = 0; c < 10; ++c) acc[c] = bs[c];
  const float* f = F + n * 192;
  for (int j = 0; j < 192; j += 4) {
    float4 v = *reinterpret_cast<const float4*>(f + j);
#pragma unroll
    for (int c = 0; c < 10; ++c)
      acc[c] += v.x * Ws[(j + 0) * 10 + c] + v.y * Ws[(j + 1) * 10 + c] +
                v.z * Ws[(j + 2) * 10 + c] + v.w * Ws[(j + 3) * 10 + c];
  }
  float m = acc[0];
#pragma unroll
  for (int c = 1; c < 10; ++c) m = fmaxf(m, acc[c]);
  float s = 0.f;
  float e[10];
#pragma unroll
  for (int c = 0; c < 10; ++c) {
    e[c] = exp2f((acc[c] - m) * LOG2E_);
    s += e[c];
  }
  float inv = 1.f / s;
#pragma unroll
  for (int c = 0; c < 10; ++c) out[n * 10 + c] = e[c] * inv;
}

extern "C" void kernel_launch(void* const* d_in, const int* in_sizes, int n_in,
                              void* d_out, int out_size, void* d_ws, size_t ws_size,
                              hipStream_t stream) {
  const float* series = (const float*)d_in[0];  // [512, 2048]
  const float* shp1 = (const float*)d_in[1];    // [64, 32]
  const float* shp2 = (const float*)d_in[2];    // [64, 64]
  const float* shp3 = (const float*)d_in[3];    // [64, 96]
  const float* Wm = (const float*)d_in[4];      // [192, 10]
  const float* bv = (const float*)d_in[5];      // [10]
  float* out = (float*)d_out;                   // [512, 10] f32
  float* F = (float*)d_ws;                      // [512, 192] features

  feat_kernel<<<dim3(512, 3), 256, 0, stream>>>(series, shp1, shp2, shp3, F);
  logits_kernel<<<2, 256, 0, stream>>>(F, Wm, bv, out);
}